// Round 1
// baseline (1270.687 us; speedup 1.0000x reference)
//
#include <hip/hip_runtime.h>
#include <math.h>

#define T_LEN 2048
#define HID   15
#define E_DIM 300
#define NGATE 60   // 4*HID

// d_ws layout: pregates[2][T_LEN][HID][4] floats  (i,f,g,o per cell), ~983 KB

__global__ __launch_bounds__(64) void pregate_kernel(
    const int* __restrict__ s1, const int* __restrict__ s2,
    const float* __restrict__ emb, const float* __restrict__ W_ih,
    const float* __restrict__ b_ih, const float* __restrict__ b_hh,
    float* __restrict__ pg)
{
    int b   = blockIdx.x;          // 0..4095
    int seq = b >> 11;             // b / 2048
    int t   = b & 2047;
    int tok = (seq ? s2 : s1)[t];

    __shared__ float4 x[E_DIM / 4];   // 75 x float4 = 300 floats
    const float4* erow = (const float4*)(emb + (size_t)tok * E_DIM);
    for (int e = threadIdx.x; e < E_DIM / 4; e += 64) x[e] = erow[e];
    __syncthreads();

    int g = threadIdx.x;
    if (g < NGATE) {
        const float4* w = (const float4*)(W_ih + (size_t)g * E_DIM);
        float a0 = 0.f, a1 = 0.f, a2 = 0.f, a3 = 0.f;
        #pragma unroll 5
        for (int e = 0; e < E_DIM / 4; ++e) {
            float4 wv = w[e];
            float4 xv = x[e];
            a0 = fmaf(wv.x, xv.x, a0);
            a1 = fmaf(wv.y, xv.y, a1);
            a2 = fmaf(wv.z, xv.z, a2);
            a3 = fmaf(wv.w, xv.w, a3);
        }
        float acc = (a0 + a1) + (a2 + a3) + b_ih[g] + b_hh[g];
        int cell = g % HID;        // 0..14
        int part = g / HID;        // 0=i 1=f 2=g 3=o
        pg[(((size_t)seq * T_LEN + t) * HID + cell) * 4 + part] = acc;
    }
}

__device__ __forceinline__ float sig_fast(float x) {
    return 1.0f / (1.0f + __expf(-x));
}
__device__ __forceinline__ float tanh_fast(float x) {
    // stable for large |x|: exp(2x)->inf gives 1, ->0 gives -1
    return 1.0f - 2.0f / (__expf(2.0f * x) + 1.0f);
}
__device__ __forceinline__ float bcast(float v, int lane) {
    return __int_as_float(__builtin_amdgcn_readlane(__float_as_int(v), lane));
}

__global__ __launch_bounds__(128) void scan_head_kernel(
    const float* __restrict__ pg,     // [2][T][HID][4]
    const float* __restrict__ W_hh,   // [60][15]
    const float* __restrict__ h1_0, const float* __restrict__ c1_0,
    const float* __restrict__ h2_0, const float* __restrict__ c2_0,
    const float* __restrict__ W1, const float* __restrict__ b1,
    const float* __restrict__ W2, const float* __restrict__ b2,
    float* __restrict__ out)
{
    const int w    = threadIdx.x >> 6;   // wave id = sequence id
    const int lane = threadIdx.x & 63;
    const int j    = lane < HID ? lane : HID - 1;   // clamp idle lanes (safe loads)

    // Per-lane recurrent weights: rows j (i), 15+j (f), 30+j (g), 45+j (o)
    float wi[HID], wf[HID], wg[HID], wo[HID];
    #pragma unroll
    for (int k = 0; k < HID; ++k) {
        wi[k] = W_hh[(0 * HID + j) * HID + k];
        wf[k] = W_hh[(1 * HID + j) * HID + k];
        wg[k] = W_hh[(2 * HID + j) * HID + k];
        wo[k] = W_hh[(3 * HID + j) * HID + k];
    }

    float h = (w ? h2_0 : h1_0)[j];
    float c = (w ? c2_0 : c1_0)[j];

    const float4* pgp = ((const float4*)pg) + ((size_t)w * T_LEN * HID + j);

    // software pipeline the pre-gate loads 2 steps ahead
    float4 cur = pgp[0];
    float4 n1  = pgp[1 * HID];

    for (int t = 0; t < T_LEN; ++t) {
        int tn = t + 2;
        if (tn > T_LEN - 1) tn = T_LEN - 1;
        float4 n2 = pgp[(size_t)tn * HID];   // issued before the serial chain

        float ai = cur.x, af = cur.y, ag = cur.z, ao = cur.w;
        #pragma unroll
        for (int k = 0; k < HID; ++k) {
            float hk = bcast(h, k);          // v_readlane -> SGPR broadcast
            ai = fmaf(wi[k], hk, ai);
            af = fmaf(wf[k], hk, af);
            ag = fmaf(wg[k], hk, ag);
            ao = fmaf(wo[k], hk, ao);
        }
        float ig = sig_fast(ai);
        float fg = sig_fast(af);
        float gg = tanh_fast(ag);
        float og = sig_fast(ao);
        c = fmaf(fg, c, ig * gg);
        h = og * tanh_fast(c);

        cur = n1; n1 = n2;
    }

    // ---- head: vec[75] -> hidden[25] -> out[2] ----
    __shared__ float hs[2][HID];
    __shared__ float vec[5 * HID];
    __shared__ float hid[25];

    if (lane < HID) hs[w][lane] = h;
    __syncthreads();

    int tid = threadIdx.x;
    if (tid < 5 * HID) {
        int p = tid / HID, k = tid % HID;
        float a = hs[0][k], b = hs[1][k];
        float v = (p == 0) ? a
                : (p == 1) ? fabsf(a - b)
                : (p == 2) ? b
                : (p == 3) ? a * b
                :            0.5f * (a + b);
        vec[tid] = v;
    }
    __syncthreads();
    if (tid < 25) {
        float acc = b1[tid];
        #pragma unroll 5
        for (int k = 0; k < 75; ++k) acc = fmaf(W1[tid * 75 + k], vec[k], acc);
        hid[tid] = acc;
    }
    __syncthreads();
    if (tid < 2) {
        float acc = b2[tid];
        #pragma unroll
        for (int k = 0; k < 25; ++k) acc = fmaf(W2[tid * 25 + k], hid[k], acc);
        out[tid] = acc;
    }
}

extern "C" void kernel_launch(void* const* d_in, const int* in_sizes, int n_in,
                              void* d_out, int out_size, void* d_ws, size_t ws_size,
                              hipStream_t stream) {
    const int*   s1   = (const int*)d_in[0];
    const int*   s2   = (const int*)d_in[1];
    const float* emb  = (const float*)d_in[2];
    const float* W_ih = (const float*)d_in[3];
    const float* W_hh = (const float*)d_in[4];
    const float* b_ih = (const float*)d_in[5];
    const float* b_hh = (const float*)d_in[6];
    const float* W1   = (const float*)d_in[7];
    const float* b1   = (const float*)d_in[8];
    const float* W2   = (const float*)d_in[9];
    const float* b2   = (const float*)d_in[10];
    const float* h1_0 = (const float*)d_in[11];
    const float* c1_0 = (const float*)d_in[12];
    const float* h2_0 = (const float*)d_in[13];
    const float* c2_0 = (const float*)d_in[14];

    float* pg = (float*)d_ws;   // needs 2*2048*15*4*4 = 983040 bytes

    pregate_kernel<<<dim3(2 * T_LEN), dim3(64), 0, stream>>>(
        s1, s2, emb, W_ih, b_ih, b_hh, pg);
    scan_head_kernel<<<dim3(1), dim3(128), 0, stream>>>(
        pg, W_hh, h1_0, c1_0, h2_0, c2_0, W1, b1, W2, b2, (float*)d_out);
}

// Round 2
// 824.961 us; speedup vs baseline: 1.5403x; 1.5403x over previous
//
#include <hip/hip_runtime.h>
#include <math.h>

#define T_LEN  2048
#define HID    15
#define E_DIM  300
#define NGATE  60          // 4*HID
#define CHUNK  64
#define NCHUNK (T_LEN / CHUNK)   // 32

// d_ws layout: pregates[2][T_LEN][HID][4] floats (i,f,g,o per cell), ~983 KB

__global__ __launch_bounds__(64) void pregate_kernel(
    const int* __restrict__ s1, const int* __restrict__ s2,
    const float* __restrict__ emb, const float* __restrict__ W_ih,
    const float* __restrict__ b_ih, const float* __restrict__ b_hh,
    float* __restrict__ pg)
{
    int b   = blockIdx.x;          // 0..4095
    int seq = b >> 11;             // b / 2048
    int t   = b & 2047;
    int tok = (seq ? s2 : s1)[t];

    __shared__ float4 x[E_DIM / 4];   // 75 x float4 = 300 floats
    const float4* erow = (const float4*)(emb + (size_t)tok * E_DIM);
    for (int e = threadIdx.x; e < E_DIM / 4; e += 64) x[e] = erow[e];
    __syncthreads();

    int g = threadIdx.x;
    if (g < NGATE) {
        const float4* w = (const float4*)(W_ih + (size_t)g * E_DIM);
        float a0 = 0.f, a1 = 0.f, a2 = 0.f, a3 = 0.f;
        #pragma unroll 5
        for (int e = 0; e < E_DIM / 4; ++e) {
            float4 wv = w[e];
            float4 xv = x[e];
            a0 = fmaf(wv.x, xv.x, a0);
            a1 = fmaf(wv.y, xv.y, a1);
            a2 = fmaf(wv.z, xv.z, a2);
            a3 = fmaf(wv.w, xv.w, a3);
        }
        float acc = (a0 + a1) + (a2 + a3) + b_ih[g] + b_hh[g];
        int cell = g % HID;        // 0..14
        int part = g / HID;        // 0=i 1=f 2=g 3=o
        pg[(((size_t)seq * T_LEN + t) * HID + cell) * 4 + part] = acc;
    }
}

__device__ __forceinline__ float sig_fast(float x) {
    return 1.0f / (1.0f + __expf(-x));
}
__device__ __forceinline__ float tanh_fast(float x) {
    return 1.0f - 2.0f / (__expf(2.0f * x) + 1.0f);
}
__device__ __forceinline__ float bcast(float v, int lane) {
    return __int_as_float(__builtin_amdgcn_readlane(__float_as_int(v), lane));
}

// 60 recurrent weights as NAMED SCALARS so SROA/regalloc must keep them in
// VGPRs (R0's array version left VGPR_Count=44 -> scratch/remat on the serial
// chain, ~1260 cyc/step).
#define DECLW(k) const float wik##k = Wi[k], wfk##k = Wf[k], \
                             wgk##k = Wg[k], wok##k = Wo[k];
#define GSTEP(k, AI, AF, AG, AO) { \
    const float hk = bcast(h, k);  \
    AI = fmaf(wik##k, hk, AI);     \
    AF = fmaf(wfk##k, hk, AF);     \
    AG = fmaf(wgk##k, hk, AG);     \
    AO = fmaf(wok##k, hk, AO); }

__global__ __launch_bounds__(256) void scan_head_kernel(
    const float* __restrict__ pg,     // [2][T][HID][4]
    const float* __restrict__ W_hh,   // [60][15]
    const float* __restrict__ h1_0, const float* __restrict__ c1_0,
    const float* __restrict__ h2_0, const float* __restrict__ c2_0,
    const float* __restrict__ W1, const float* __restrict__ b1,
    const float* __restrict__ W2, const float* __restrict__ b2,
    float* __restrict__ out)
{
    // double-buffered pre-gate staging: [seq][buf][step*HID + cell] as float4
    __shared__ float4 pgbuf[2][2][CHUNK * HID];   // 61440 B
    __shared__ float hs[2][HID];
    __shared__ float vec[5 * HID];
    __shared__ float hid[25];

    const int wv   = threadIdx.x >> 6;   // 0,1 = scan waves; 2,3 = loader waves
    const int lane = threadIdx.x & 63;

    float h = 0.f;  // only meaningful on scan waves, lanes 0..14

    if (wv >= 2) {
        // ---- producer: stream pg chunks into LDS, double-buffered ----
        const int seq = wv - 2;
        const float4* src = ((const float4*)pg) + (size_t)seq * T_LEN * HID;
        for (int ch = 0; ch < NCHUNK; ++ch) {
            float4* dst = &pgbuf[seq][ch & 1][0];
            const float4* s = src + (size_t)ch * CHUNK * HID;
            #pragma unroll
            for (int i = 0; i < (CHUNK * HID) / 64; ++i)   // 15 iters
                dst[i * 64 + lane] = s[i * 64 + lane];
            __syncthreads();   // chunk ch ready; consumer done with this buf
        }
    } else {
        // ---- consumer: serial LSTM scan, one wave per sequence ----
        const int seq = wv;
        const int j = lane < HID ? lane : HID - 1;   // clamp idle lanes

        const float* Wi = W_hh + (0 * HID + j) * HID;
        const float* Wf = W_hh + (1 * HID + j) * HID;
        const float* Wg = W_hh + (2 * HID + j) * HID;
        const float* Wo = W_hh + (3 * HID + j) * HID;
        DECLW(0)  DECLW(1)  DECLW(2)  DECLW(3)  DECLW(4)
        DECLW(5)  DECLW(6)  DECLW(7)  DECLW(8)  DECLW(9)
        DECLW(10) DECLW(11) DECLW(12) DECLW(13) DECLW(14)

        h       = (seq ? h2_0 : h1_0)[j];
        float c = (seq ? c2_0 : c1_0)[j];

        for (int ch = 0; ch < NCHUNK; ++ch) {
            __syncthreads();   // wait: chunk ch staged in pgbuf[seq][ch&1]
            if (lane < 16) {   // mask off upper lanes for the serial body
                const float4* B = &pgbuf[seq][ch & 1][0];
                float4 cur = B[j];
                float4 n1  = B[HID + j];
                for (int t = 0; t < CHUNK; ++t) {
                    int tn = t + 2;
                    if (tn > CHUNK - 1) tn = CHUNK - 1;
                    float4 n2 = B[tn * HID + j];   // depth-2 LDS prefetch

                    // split accumulators: chain 15 FMAs -> 8 (parallel halves)
                    float aiA = cur.x, afA = cur.y, agA = cur.z, aoA = cur.w;
                    float aiB = 0.f, afB = 0.f, agB = 0.f, aoB = 0.f;
                    GSTEP(0,  aiA, afA, agA, aoA)
                    GSTEP(1,  aiA, afA, agA, aoA)
                    GSTEP(2,  aiA, afA, agA, aoA)
                    GSTEP(3,  aiA, afA, agA, aoA)
                    GSTEP(4,  aiA, afA, agA, aoA)
                    GSTEP(5,  aiA, afA, agA, aoA)
                    GSTEP(6,  aiA, afA, agA, aoA)
                    GSTEP(7,  aiA, afA, agA, aoA)
                    GSTEP(8,  aiB, afB, agB, aoB)
                    GSTEP(9,  aiB, afB, agB, aoB)
                    GSTEP(10, aiB, afB, agB, aoB)
                    GSTEP(11, aiB, afB, agB, aoB)
                    GSTEP(12, aiB, afB, agB, aoB)
                    GSTEP(13, aiB, afB, agB, aoB)
                    GSTEP(14, aiB, afB, agB, aoB)
                    float ai = aiA + aiB, af = afA + afB;
                    float ag = agA + agB, ao = aoA + aoB;

                    float ig = sig_fast(ai);
                    float fg = sig_fast(af);
                    float gg = tanh_fast(ag);
                    float og = sig_fast(ao);
                    c = fmaf(fg, c, ig * gg);
                    h = og * tanh_fast(c);

                    cur = n1; n1 = n2;
                }
            }
        }
        if (lane < HID) hs[seq][lane] = h;
    }

    __syncthreads();   // hs ready (barrier #NCHUNK+1 for everyone)

    // ---- head: vec[75] -> hidden[25] -> out[2] ----
    int tid = threadIdx.x;
    if (tid < 5 * HID) {
        int p = tid / HID, k = tid % HID;
        float a = hs[0][k], b = hs[1][k];
        float v = (p == 0) ? a
                : (p == 1) ? fabsf(a - b)
                : (p == 2) ? b
                : (p == 3) ? a * b
                :            0.5f * (a + b);
        vec[tid] = v;
    }
    __syncthreads();
    if (tid < 25) {
        float acc = b1[tid];
        #pragma unroll 5
        for (int k = 0; k < 75; ++k) acc = fmaf(W1[tid * 75 + k], vec[k], acc);
        hid[tid] = acc;
    }
    __syncthreads();
    if (tid < 2) {
        float acc = b2[tid];
        #pragma unroll
        for (int k = 0; k < 25; ++k) acc = fmaf(W2[tid * 25 + k], hid[k], acc);
        out[tid] = acc;
    }
}

extern "C" void kernel_launch(void* const* d_in, const int* in_sizes, int n_in,
                              void* d_out, int out_size, void* d_ws, size_t ws_size,
                              hipStream_t stream) {
    const int*   s1   = (const int*)d_in[0];
    const int*   s2   = (const int*)d_in[1];
    const float* emb  = (const float*)d_in[2];
    const float* W_ih = (const float*)d_in[3];
    const float* W_hh = (const float*)d_in[4];
    const float* b_ih = (const float*)d_in[5];
    const float* b_hh = (const float*)d_in[6];
    const float* W1   = (const float*)d_in[7];
    const float* b1   = (const float*)d_in[8];
    const float* W2   = (const float*)d_in[9];
    const float* b2   = (const float*)d_in[10];
    const float* h1_0 = (const float*)d_in[11];
    const float* c1_0 = (const float*)d_in[12];
    const float* h2_0 = (const float*)d_in[13];
    const float* c2_0 = (const float*)d_in[14];

    float* pg = (float*)d_ws;   // 2*2048*15*4*4 = 983040 bytes

    pregate_kernel<<<dim3(2 * T_LEN), dim3(64), 0, stream>>>(
        s1, s2, emb, W_ih, b_ih, b_hh, pg);
    scan_head_kernel<<<dim3(1), dim3(256), 0, stream>>>(
        pg, W_hh, h1_0, c1_0, h2_0, c2_0, W1, b1, W2, b2, (float*)d_out);
}